// Round 14
// baseline (321.470 us; speedup 1.0000x reference)
//
#include <hip/hip_runtime.h>

#define SIG0 0.17f
#define SIG1 4.86f

__device__ __constant__ float c_filt0[25] = {
  0.04f,0.04f,0.05f,0.04f,0.04f,
  0.04f,0.03f,0.04f,0.03f,0.04f,
  0.05f,0.04f,0.05f,0.04f,0.05f,
  0.04f,0.03f,0.04f,0.03f,0.04f,
  0.04f,0.04f,0.05f,0.04f,0.04f};
__device__ __constant__ float c_f1d[5] = {0.05f,0.25f,0.4f,0.25f,0.05f};

static __device__ __forceinline__ int iclamp(int v, int lo, int hi){
  return v < lo ? lo : (v > hi ? hi : v);
}
static __device__ __forceinline__ float4 gamma4(float4 v){
  const float e = 0.3846153846153846f;
  v.x = __powf(v.x, e); v.y = __powf(v.y, e);
  v.z = __powf(v.z, e); v.w = __powf(v.w, e);
  return v;
}

// Padded level buffers: size S stored (S+4) x (S+8); logical (y,x) at [(y+2)*(S+8)+(x+4)].
// g1: S=256 stride 264 (img 68640); g2: S=128 stride 136 (17952); g3: S=64 stride 72 (4896)

// ================= k_d1: gamma + down0 =================
__global__ __launch_bounds__(256)
void k_d1(const float* __restrict__ hin, const float* __restrict__ lin,
          float* __restrict__ g1){
  extern __shared__ float sm[];
  float* ST = sm;            // [20][520]
  float* HS = sm + 20*520;   // [20][256]
  int bx = blockIdx.x, z = blockIdx.y;
  const float* in = (z<16)? hin + (size_t)z*262144 : lin + (size_t)(z-16)*262144;
  float* out0 = g1 + (size_t)z*68640;
  int t = threadIdx.x;
  for (int f=t; f<2560; f+=256){
    int r = f>>7, ch = f&127;
    int yy = iclamp(16*bx-2+r, 0, 511);
    float4 v = *(const float4*)&in[(size_t)yy*512 + 4*ch];
    *(float4*)&ST[r*520 + 4 + 4*ch] = gamma4(v);
  }
  __syncthreads();
  if (t < 20){
    float vl = ST[t*520 + 4],  vr = ST[t*520 + 515];
    float4 v4l = {vl,vl,vl,vl}, v4r = {vr,vr,vr,vr};
    *(float4*)&ST[t*520 + 0]   = v4l;
    *(float4*)&ST[t*520 + 516] = v4r;
  }
  __syncthreads();
  for (int f=t; f<5120; f+=256){
    int r = f>>8, xo = f&255;
    const float* rp = &ST[r*520 + 2*xo + 2];
    HS[r*256 + xo] = 0.05f*rp[0]+0.25f*rp[1]+0.4f*rp[2]+0.25f*rp[3]+0.05f*rp[4];
  }
  __syncthreads();
  for (int f=t; f<2048; f+=256){
    int yo = f>>8, X = f&255;
    int Y = 8*bx + yo;
    float v = 0.05f*HS[(2*yo)*256+X]+0.25f*HS[(2*yo+1)*256+X]+0.4f*HS[(2*yo+2)*256+X]
            +0.25f*HS[(2*yo+3)*256+X]+0.05f*HS[(2*yo+4)*256+X];
    int rlo=(Y==0)?0:(Y+2), rhi=(Y==255)?259:(Y+2);
    int clo=(X==0)?0:(X+4), chi=(X==255)?263:(X+4);
    for (int rr=rlo; rr<=rhi; rr++)
      for (int cc=clo; cc<=chi; cc++)
        out0[(size_t)rr*264+cc] = v;
  }
}

// ================= generic down =================
template<int SIN>
__global__ __launch_bounds__(256)
void k_down(const float* __restrict__ gin, float* __restrict__ gout){
  constexpr int WI = SIN+8, SO = SIN/2, PO = SO+8;
  constexpr int CH = WI/4;
  extern __shared__ float sm[];
  float* ST = sm;
  float* HS = sm + 20*WI;
  int bx = blockIdx.x, z = blockIdx.y;
  const float* in0 = gin + (size_t)z * (size_t)((SIN+4)*WI);
  float* out0 = gout + (size_t)z * (size_t)((SO+4)*PO);
  int t = threadIdx.x;
  for (int f=t; f<20*CH; f+=256){
    int r = f/CH, ch = f - r*CH;
    *(float4*)&ST[r*WI + 4*ch] = *(const float4*)&in0[(size_t)(16*bx + r)*WI + 4*ch];
  }
  __syncthreads();
  for (int f=t; f<20*SO; f+=256){
    int r = f/SO, xo = f - r*SO;
    const float* rp = &ST[r*WI + 2*xo + 2];
    HS[r*SO + xo] = 0.05f*rp[0]+0.25f*rp[1]+0.4f*rp[2]+0.25f*rp[3]+0.05f*rp[4];
  }
  __syncthreads();
  for (int f=t; f<8*SO; f+=256){
    int yo = f/SO, X = f - yo*SO;
    int Y = 8*bx + yo;
    float v = 0.05f*HS[(2*yo)*SO+X]+0.25f*HS[(2*yo+1)*SO+X]+0.4f*HS[(2*yo+2)*SO+X]
            +0.25f*HS[(2*yo+3)*SO+X]+0.05f*HS[(2*yo+4)*SO+X];
    int rlo=(Y==0)?0:(Y+2), rhi=(Y==SO-1)?(SO+3):(Y+2);
    int clo=(X==0)?0:(X+4), chi=(X==SO-1)?(SO+7):(X+4);
    for (int rr=rlo; rr<=rhi; rr++)
      for (int cc=clo; cc<=chi; cc++)
        out0[(size_t)rr*PO+cc] = v;
  }
}

// ================= fused body =================
template<int GAMMA, int SIMG, int TW, int TH>
__device__ __forceinline__ void fused_body(
    const float* __restrict__ a0, const float* __restrict__ a1,
    const float* __restrict__ s10, const float* __restrict__ s11,
    int xt, int yt, float* __restrict__ out_slot)
{
  constexpr int WL  = TW + 8;
  constexpr int W1L = TW/2 + 8;
  constexpr int PS1 = SIMG/2 + 8;
  constexpr int NR  = TH + 4;
  constexpr int NR1 = TH/2 + 4;
  constexpr int PRS = NR/2;
  constexpr int NSEG= WL/8;
  constexpr int NQX = TW/4;
  constexpr int LQX = (NQX==64)?6:5;
  constexpr int QY  = TH/2;
  constexpr int CH  = WL/4;
  constexpr int CH1 = W1L/4;
  extern __shared__ float sm[];
  float* SG  = sm;
  float* S1L = sm + 2*NR*WL;
  float* RED = S1L + 2*NR1*W1L;
  const int t = threadIdx.x;
  const int x0 = TW*xt, y0 = TH*yt;

  if (GAMMA){
    for (int f=t; f<2*NR*CH; f+=256){
      int img = f >= NR*CH; int rem = img ? f - NR*CH : f;
      int rr = rem/CH, ch = rem - rr*CH;
      int yy = iclamp(y0-2+rr, 0, SIMG-1);
      int xb = x0 - 4 + 4*ch;
      const float* rp = (img ? a1 : a0) + (size_t)yy*SIMG;
      float4 v;
      if (xb >= 0 && xb <= SIMG-4) v = *(const float4*)&rp[xb];
      else { v.x=rp[iclamp(xb,0,SIMG-1)]; v.y=rp[iclamp(xb+1,0,SIMG-1)];
             v.z=rp[iclamp(xb+2,0,SIMG-1)]; v.w=rp[iclamp(xb+3,0,SIMG-1)]; }
      *(float4*)&SG[(img*NR+rr)*WL + 4*ch] = gamma4(v);
    }
  } else {
    for (int f=t; f<2*NR*CH; f+=256){
      int img = f >= NR*CH; int rem = img ? f - NR*CH : f;
      int rr = rem/CH, ch = rem - rr*CH;
      const float* src = img ? a1 : a0;
      *(float4*)&SG[(img*NR+rr)*WL + 4*ch] =
          *(const float4*)&src[(size_t)(y0+rr)*WL + 4*ch];
    }
  }
  for (int f=t; f<2*NR1*CH1; f+=256){
    int img = f >= NR1*CH1; int rem = img ? f - NR1*CH1 : f;
    int ro = rem/CH1, ch = rem - ro*CH1;
    const float* src = img ? s11 : s10;
    *(float4*)&S1L[(img*NR1+ro)*W1L + 4*ch] =
        *(const float4*)&src[(size_t)(y0/2+ro)*PS1 + x0/2 + 4*ch];
  }
  __syncthreads();

  for (int f=t; f<2*PRS*NSEG; f+=256){
    int img = f >= PRS*NSEG; int rem = img ? f - PRS*NSEG : f;
    int p = rem/NSEG, q = rem - p*NSEG;
    const float* s1b = S1L + img*NR1*W1L;
    float A[8], B[8], C[8];
    {
      const float* pr = s1b + p*W1L + 4*q;
      float4 t0 = *(const float4*)&pr[0];
      float4 t1 = *(const float4*)&pr[4];
      A[0]=t0.x; A[1]=t0.y; A[2]=t0.z; A[3]=t0.w;
      A[4]=t1.x; A[5]=t1.y; A[6]=t1.z; A[7]=t1.w;
    }
    {
      const float* pr = s1b + (p+1)*W1L + 4*q;
      float4 t0 = *(const float4*)&pr[0];
      float4 t1 = *(const float4*)&pr[4];
      B[0]=t0.x; B[1]=t0.y; B[2]=t0.z; B[3]=t0.w;
      B[4]=t1.x; B[5]=t1.y; B[6]=t1.z; B[7]=t1.w;
    }
    {
      const float* pr = s1b + (p+2)*W1L + 4*q;
      float4 t0 = *(const float4*)&pr[0];
      float4 t1 = *(const float4*)&pr[4];
      C[0]=t0.x; C[1]=t0.y; C[2]=t0.z; C[3]=t0.w;
      C[4]=t1.x; C[5]=t1.y; C[6]=t1.z; C[7]=t1.w;
    }
    float ue[8], uo[8];
    #pragma unroll
    for (int j=0;j<4;j++){
      float hEA = 0.05f*A[j+1]+0.4f*A[j+2]+0.05f*A[j+3];
      float hEB = 0.05f*B[j+1]+0.4f*B[j+2]+0.05f*B[j+3];
      float hEC = 0.05f*C[j+1]+0.4f*C[j+2]+0.05f*C[j+3];
      float hOA = 0.25f*(A[j+2]+A[j+3]);
      float hOB = 0.25f*(B[j+2]+B[j+3]);
      float hOC = 0.25f*(C[j+2]+C[j+3]);
      ue[2*j]   = 0.2f*hEA + 1.6f*hEB + 0.2f*hEC;
      ue[2*j+1] = 0.2f*hOA + 1.6f*hOB + 0.2f*hOC;
      uo[2*j]   = hEB + hEC;
      uo[2*j+1] = hOB + hOC;
    }
    float* re = SG + (img*NR + 2*p)*WL + 8*q;
    float* ro_ = SG + (img*NR + 2*p+1)*WL + 8*q;
    {
      float4 e0 = *(float4*)&re[0];
      float4 e1 = *(float4*)&re[4];
      e0.x -= ue[0]; e0.y -= ue[1]; e0.z -= ue[2]; e0.w -= ue[3];
      e1.x -= ue[4]; e1.y -= ue[5]; e1.z -= ue[6]; e1.w -= ue[7];
      *(float4*)&re[0] = e0; *(float4*)&re[4] = e1;
    }
    {
      float4 o0 = *(float4*)&ro_[0];
      float4 o1 = *(float4*)&ro_[4];
      o0.x -= uo[0]; o0.y -= uo[1]; o0.z -= uo[2]; o0.w -= uo[3];
      o1.x -= uo[4]; o1.y -= uo[5]; o1.z -= uo[6]; o1.w -= uo[7];
      *(float4*)&ro_[0] = o0; *(float4*)&ro_[4] = o1;
    }
  }
  __syncthreads();

  {
    bool top = (y0 == 0), bot = (y0 + TH == SIMG);
    if (top | bot){
      for (int f=t; f<2*CH; f+=256){
        int img = f >= CH; int ch = img ? f - CH : f;
        float* base = SG + img*NR*WL;
        if (top){ float4 v = *(float4*)&base[2*WL + 4*ch];
          *(float4*)&base[0*WL + 4*ch] = v; *(float4*)&base[1*WL + 4*ch] = v; }
        if (bot){ float4 v = *(float4*)&base[(TH+1)*WL + 4*ch];
          *(float4*)&base[(TH+2)*WL + 4*ch] = v; *(float4*)&base[(TH+3)*WL + 4*ch] = v; }
      }
    }
  }
  __syncthreads();
  {
    bool lft = (x0 == 0), rgt = (x0 + TW == SIMG);
    if ((lft | rgt) && t < 2*NR){
      int img = t >= NR; int r = img ? t - NR : t;
      float* row = SG + (img*NR + r)*WL;
      if (lft){ float v = row[4];    float4 v4 = {v,v,v,v}; *(float4*)&row[0]    = v4; }
      if (rgt){ float v = row[WL-5]; float4 v4 = {v,v,v,v}; *(float4*)&row[WL-4] = v4; }
    }
  }
  __syncthreads();

  float vacc = 0.f;
  constexpr int P3N = 2*NQX*QY;
  #pragma unroll
  for (int k=0; k<P3N/256; k++){
    int u = t + 256*k;
    int img = u & 1;
    int quad = u >> 1;
    int qx = quad & (NQX-1);
    int qy = quad >> LQX;
    const float* sgb = SG + img*NR*WL;
    int cb = 4*qx, rb = 2*qy;
    float T0[4]={0,0,0,0}, T1[4]={0,0,0,0};
    float s5a[4], s5b[4], s3a[4], s3b[4], n0[4], n1[4];
    #pragma unroll
    for (int r=0;r<6;r++){
      const float* rp = &sgb[(rb+r)*WL + cb];
      float4 t0 = *(const float4*)&rp[0];
      float4 t1 = *(const float4*)&rp[4];
      float4 t2 = *(const float4*)&rp[8];
      float w[12];
      w[0]=t0.x; w[1]=t0.y; w[2]=t0.z;  w[3]=t0.w;
      w[4]=t1.x; w[5]=t1.y; w[6]=t1.z;  w[7]=t1.w;
      w[8]=t2.x; w[9]=t2.y; w[10]=t2.z; w[11]=t2.w;
      float aw[8];
      #pragma unroll
      for (int j=0;j<8;j++) aw[j] = fabsf(w[j+2]);
      float h0 = ((aw[0]+aw[1])+(aw[2]+aw[3]))+aw[4];
      float h1 = h0 - aw[0] + aw[5];
      float h2 = h1 - aw[1] + aw[6];
      float h3 = h2 - aw[2] + aw[7];
      float hh[4] = {h0,h1,h2,h3};
      if (r<=4){
        #pragma unroll
        for (int c=0;c<4;c++) T0[c] += hh[c];
      }
      if (r>=1){
        #pragma unroll
        for (int c=0;c<4;c++) T1[c] += hh[c];
      }
      if (r==0){
        #pragma unroll
        for (int c=0;c<4;c++) s5a[c] = aw[c+2];
      }
      if (r==1){
        #pragma unroll
        for (int c=0;c<4;c++){ s3a[c] = aw[c+1]+aw[c+3]; s5b[c] = aw[c+2]; }
      }
      if (r==2){
        #pragma unroll
        for (int c=0;c<4;c++){ s5a[c] += aw[c]+aw[c+2]+aw[c+4]; n0[c]=w[c+4]; s3b[c] = aw[c+1]+aw[c+3]; }
      }
      if (r==3){
        #pragma unroll
        for (int c=0;c<4;c++){ s3a[c] += aw[c+1]+aw[c+3]; s5b[c] += aw[c]+aw[c+2]+aw[c+4]; n1[c]=w[c+4]; }
      }
      if (r==4){
        #pragma unroll
        for (int c=0;c<4;c++){ s5a[c] += aw[c+2]; s3b[c] += aw[c+1]+aw[c+3]; }
      }
      if (r==5){
        #pragma unroll
        for (int c=0;c<4;c++) s5b[c] += aw[c+2];
      }
    }
    float qv[8];
    #pragma unroll
    for (int c=0;c<4;c++){
      float d0 = SIG0 + 0.04f*T0[c] + 0.01f*s5a[c] - 0.01f*s3a[c];
      float d1 = SIG0 + 0.04f*T1[c] + 0.01f*s5b[c] - 0.01f*s3b[c];
      qv[c]   = __fdividef(n0[c], d0);
      qv[4+c] = __fdividef(n1[c], d1);
    }
    #pragma unroll
    for (int i=0;i<8;i++){
      float o = __shfl_xor(qv[i], 1);
      float d = qv[i] - o;
      vacc += d*d;
    }
  }
  if (t & 1) vacc = 0.f;
  #pragma unroll
  for (int off=32; off>0; off>>=1) vacc += __shfl_down(vacc, off);
  if ((t&63)==0) RED[t>>6] = vacc;
  __syncthreads();
  if (t==0)
    out_slot[0] = RED[0]+RED[1]+RED[2]+RED[3];
}

// ---- fused wrappers ----
__global__ __launch_bounds__(256)
void k_fused0(const float* __restrict__ h, const float* __restrict__ l,
              const float* __restrict__ g1, float* __restrict__ p0){
  int xt = blockIdx.x, yt = blockIdx.y, z = blockIdx.z;
  fused_body<1,512,256,16>(h + (size_t)z*262144, l + (size_t)z*262144,
                           g1 + (size_t)z*68640, g1 + (size_t)(z+16)*68640,
                           xt, yt, p0 + z*64 + yt*2 + xt);
}
__global__ __launch_bounds__(256)
void k_fused1(const float* __restrict__ g1, const float* __restrict__ g2,
              float* __restrict__ p1){
  int yt = blockIdx.x, z = blockIdx.y;
  fused_body<0,256,256,8>(g1 + (size_t)z*68640, g1 + (size_t)(z+16)*68640,
                          g2 + (size_t)z*17952, g2 + (size_t)(z+16)*17952,
                          0, yt, p1 + z*32 + yt);
}
__global__ __launch_bounds__(256)
void k_fused2(const float* __restrict__ g2, const float* __restrict__ g3,
              float* __restrict__ p2s){
  int yt = blockIdx.x, z = blockIdx.y;
  fused_body<0,128,128,8>(g2 + (size_t)z*17952, g2 + (size_t)(z+16)*17952,
                          g3 + (size_t)z*4896, g3 + (size_t)(z+16)*4896,
                          0, yt, p2s + z*16 + yt);
}

// ================= tail (levels 3..6) =================
struct TS {
  float A3[2][64][66];
  float A4[2][32][34];
  float A5[2][16][18];
  float A6[2][8][10];
  float red[4];
};

static __device__ __forceinline__ void down_lds(const float* Ain, int ldi, int Sin,
                                                float* Aout, int ldo, int Sout,
                                                int tid, int NT){
  int tot = 2*Sout*Sout;
  for (int f=tid; f<tot; f+=NT){
    int img = f/(Sout*Sout), rem = f%(Sout*Sout), y=rem/Sout, x=rem%Sout;
    const float* A = Ain + img*Sin*ldi;
    float s=0.f;
    #pragma unroll
    for (int i=0;i<5;i++){
      int yy=iclamp(2*y+i-2,0,Sin-1);
      float rs=0.f;
      #pragma unroll
      for (int j=0;j<5;j++){
        int xx=iclamp(2*x+j-2,0,Sin-1);
        rs += c_f1d[j]*A[yy*ldi+xx];
      }
      s += c_f1d[i]*rs;
    }
    Aout[img*Sout*ldo + y*ldo + x] = s;
  }
}
static __device__ __forceinline__ void lap_lds(float* Ak, int ldk, int S,
                                               const float* Ag, int ldg,
                                               int tid, int NT){
  int Sg = S>>1;
  int tot = 2*S*S;
  for (int f=tid; f<tot; f+=NT){
    int img=f/(S*S), rem=f%(S*S), y=rem/S, x=rem%S;
    const float* G = Ag + img*Sg*ldg;
    int y2=y>>1, x2=x>>1;
    int ry0,ry1,ry2; float wy0,wy1,wy2;
    if (!(y&1)){ ry0=iclamp(y2-1,0,Sg-1); ry1=y2; ry2=iclamp(y2+1,0,Sg-1); wy0=0.2f; wy1=1.6f; wy2=0.2f; }
    else { ry0=y2; ry1=iclamp(y2+1,0,Sg-1); ry2=y2; wy0=1.f; wy1=1.f; wy2=0.f; }
    int cx0,cx1,cx2; float wx0,wx1,wx2;
    if (!(x&1)){ cx0=iclamp(x2-1,0,Sg-1); cx1=x2; cx2=iclamp(x2+1,0,Sg-1); wx0=0.05f; wx1=0.4f; wx2=0.05f; }
    else { cx0=x2; cx1=iclamp(x2+1,0,Sg-1); cx2=x2; wx0=0.25f; wx1=0.25f; wx2=0.f; }
    float u0 = wx0*G[ry0*ldg+cx0]+wx1*G[ry0*ldg+cx1]+wx2*G[ry0*ldg+cx2];
    float u1 = wx0*G[ry1*ldg+cx0]+wx1*G[ry1*ldg+cx1]+wx2*G[ry1*ldg+cx2];
    float u2 = wx0*G[ry2*ldg+cx0]+wx1*G[ry2*ldg+cx1]+wx2*G[ry2*ldg+cx2];
    Ak[img*S*ldk + y*ldk + x] -= wy0*u0+wy1*u1+wy2*u2;
  }
}
static __device__ __forceinline__ float diff_lds(const float* A, int ld, int S,
                                                 int tid, int NT){
  float v=0.f;
  const float* Ah = A;
  const float* Al = A + S*ld;
  for (int f=tid; f<S*S; f+=NT){
    int y=f/S, x=f%S;
    float dh=SIG0, dl=SIG0;
    #pragma unroll
    for (int i=0;i<5;i++){
      int yy=iclamp(y+i-2,0,S-1);
      #pragma unroll
      for (int j=0;j<5;j++){
        int xx=iclamp(x+j-2,0,S-1);
        float w=c_filt0[i*5+j];
        dh += w*fabsf(Ah[yy*ld+xx]);
        dl += w*fabsf(Al[yy*ld+xx]);
      }
    }
    float d = __fdividef(Ah[y*ld+x],dh) - __fdividef(Al[y*ld+x],dl);
    v += d*d;
  }
  return v;
}

__global__ __launch_bounds__(256)
void k_tail(const float* __restrict__ g3, float* __restrict__ accum){
  extern __shared__ char smem[];
  TS* T = (TS*)smem;
  int b = blockIdx.x;
  int tid = threadIdx.x;
  const float* s0  = g3 + (size_t)b*4896 + 148;
  const float* s1p = g3 + (size_t)(b+16)*4896 + 148;
  for (int f=tid; f<2*4096; f+=256){
    int img=f>>12, rem=f&4095, r=rem>>6, c=rem&63;
    T->A3[img][r][c] = (img? s1p : s0)[(size_t)r*72+c];
  }
  __syncthreads();
  down_lds(&T->A3[0][0][0],66,64,&T->A4[0][0][0],34,32,tid,256);
  __syncthreads();
  down_lds(&T->A4[0][0][0],34,32,&T->A5[0][0][0],18,16,tid,256);
  __syncthreads();
  down_lds(&T->A5[0][0][0],18,16,&T->A6[0][0][0],10,8,tid,256);
  __syncthreads();
  lap_lds(&T->A3[0][0][0],66,64,&T->A4[0][0][0],34,tid,256);
  __syncthreads();
  float v3 = diff_lds(&T->A3[0][0][0],66,64,tid,256);
  lap_lds(&T->A4[0][0][0],34,32,&T->A5[0][0][0],18,tid,256);
  __syncthreads();
  float v4 = diff_lds(&T->A4[0][0][0],34,32,tid,256);
  lap_lds(&T->A5[0][0][0],18,16,&T->A6[0][0][0],10,tid,256);
  __syncthreads();
  float v5 = diff_lds(&T->A5[0][0][0],18,16,tid,256);
  float v6 = 0.f;
  for (int f=tid; f<64; f+=256){
    float ch = T->A6[0][f>>3][f&7];
    float cl = T->A6[1][f>>3][f&7];
    float d = __fdividef(ch, fabsf(ch)+SIG1) - __fdividef(cl, fabsf(cl)+SIG1);
    v6 += d*d;
  }
  float vs[4] = {v3, v4, v5, v6};
  #pragma unroll
  for (int k=0;k<4;k++){
    float v = vs[k];
    #pragma unroll
    for (int off=32; off>0; off>>=1) v += __shfl_down(v, off);
    if ((tid&63)==0) T->red[tid>>6] = v;
    __syncthreads();
    if (tid==0)
      accum[(3+k)*16 + b] = T->red[0]+T->red[1]+T->red[2]+T->red[3];
    __syncthreads();
  }
}

// ================= finalize =================
__global__ __launch_bounds__(64)
void k_d6(const float* __restrict__ p0, const float* __restrict__ p1,
          const float* __restrict__ p2s, const float* __restrict__ accum,
          float* __restrict__ out){
  __shared__ float fin[16];
  int t = threadIdx.x;
  if (t < 16){
    float a0=0.f, a1=0.f, a2=0.f;
    for (int j=0;j<64;j++) a0 += p0[t*64+j];
    for (int j=0;j<32;j++) a1 += p1[t*32+j];
    for (int j=0;j<16;j++) a2 += p2s[t*16+j];
    float m = powf(a0*(1.0f/262144.0f), 0.3f)
            + powf(a1*(1.0f/65536.0f), 0.3f)
            + powf(a2*(1.0f/16384.0f), 0.3f);
    #pragma unroll
    for (int k=3;k<7;k++){
      int hw = (512>>k)*(512>>k);
      m += powf(accum[k*16+t]/(float)hw, 0.3f);
    }
    m *= (1.0f/7.0f);
    fin[t] = powf(m, 1.6666666666666667f);
  }
  __syncthreads();
  if (t == 0){
    float s = 0.f;
    #pragma unroll
    for (int i=0;i<16;i++) s += fin[i];
    out[0] = s * (1.0f/16.0f);
  }
}

// ================= DIAGNOSTIC kernels (write only to dead ws region) =================
// Instance constants of fused_body<1,512,256,16>: WL=264,W1L=136,NR=20,NR1=12,CH=66,CH1=34,
// NSEG=33,PRS=10,NQX=64,LQX=6,QY=8. MODE: 0=copy,1=+powf,2=+p2,3=+p3.
template<int MODE, int NT>
__device__ __forceinline__ void diag_body(
    const float* __restrict__ h, const float* __restrict__ l,
    const float* __restrict__ g1, float* __restrict__ dead)
{
  extern __shared__ float sm[];
  float* SG  = sm;                    // [2][20][264]
  float* S1L = sm + 10560;            // [2][12][136]
  float* RED = S1L + 3264;            // [8]
  const int t = threadIdx.x;
  int xt = blockIdx.x, yt = blockIdx.y, z = blockIdx.z;
  const int x0 = 256*xt, y0 = 16*yt;
  const float* a0 = h + (size_t)z*262144;
  const float* a1 = l + (size_t)z*262144;
  const float* s10 = g1 + (size_t)z*68640;
  const float* s11 = g1 + (size_t)(z+16)*68640;

  for (int f=t; f<2640; f+=NT){
    int img = f >= 1320; int rem = img ? f-1320 : f;
    int rr = rem/66, ch = rem - rr*66;
    int yy = iclamp(y0-2+rr, 0, 511);
    int xb = x0 - 4 + 4*ch;
    const float* rp = (img ? a1 : a0) + (size_t)yy*512;
    float4 v;
    if (xb >= 0 && xb <= 508) v = *(const float4*)&rp[xb];
    else { v.x=rp[iclamp(xb,0,511)]; v.y=rp[iclamp(xb+1,0,511)];
           v.z=rp[iclamp(xb+2,0,511)]; v.w=rp[iclamp(xb+3,0,511)]; }
    if (MODE==1) v = gamma4(v);
    *(float4*)&SG[(img*20+rr)*264 + 4*ch] = v;
  }
  for (int f=t; f<816; f+=NT){
    int img = f >= 408; int rem = img ? f-408 : f;
    int ro = rem/34, ch = rem - ro*34;
    const float* src = img ? s11 : s10;
    *(float4*)&S1L[(img*12+ro)*136 + 4*ch] =
        *(const float4*)&src[(size_t)(y0/2+ro)*264 + x0/2 + 4*ch];
  }
  __syncthreads();

  float keep = 0.f;
  if (MODE==2){
    for (int f=t; f<660; f+=NT){
      int img = f >= 330; int rem = img ? f-330 : f;
      int p = rem/33, q = rem - p*33;
      const float* s1b = S1L + img*1632;
      float A[8], B[8], C[8];
      {
        const float* pr = s1b + p*136 + 4*q;
        float4 t0 = *(const float4*)&pr[0];
        float4 t1 = *(const float4*)&pr[4];
        A[0]=t0.x; A[1]=t0.y; A[2]=t0.z; A[3]=t0.w;
        A[4]=t1.x; A[5]=t1.y; A[6]=t1.z; A[7]=t1.w;
      }
      {
        const float* pr = s1b + (p+1)*136 + 4*q;
        float4 t0 = *(const float4*)&pr[0];
        float4 t1 = *(const float4*)&pr[4];
        B[0]=t0.x; B[1]=t0.y; B[2]=t0.z; B[3]=t0.w;
        B[4]=t1.x; B[5]=t1.y; B[6]=t1.z; B[7]=t1.w;
      }
      {
        const float* pr = s1b + (p+2)*136 + 4*q;
        float4 t0 = *(const float4*)&pr[0];
        float4 t1 = *(const float4*)&pr[4];
        C[0]=t0.x; C[1]=t0.y; C[2]=t0.z; C[3]=t0.w;
        C[4]=t1.x; C[5]=t1.y; C[6]=t1.z; C[7]=t1.w;
      }
      float ue[8], uo[8];
      #pragma unroll
      for (int j=0;j<4;j++){
        float hEA = 0.05f*A[j+1]+0.4f*A[j+2]+0.05f*A[j+3];
        float hEB = 0.05f*B[j+1]+0.4f*B[j+2]+0.05f*B[j+3];
        float hEC = 0.05f*C[j+1]+0.4f*C[j+2]+0.05f*C[j+3];
        float hOA = 0.25f*(A[j+2]+A[j+3]);
        float hOB = 0.25f*(B[j+2]+B[j+3]);
        float hOC = 0.25f*(C[j+2]+C[j+3]);
        ue[2*j]   = 0.2f*hEA + 1.6f*hEB + 0.2f*hEC;
        ue[2*j+1] = 0.2f*hOA + 1.6f*hOB + 0.2f*hOC;
        uo[2*j]   = hEB + hEC;
        uo[2*j+1] = hOB + hOC;
      }
      float* re  = SG + (img*20 + 2*p)*264 + 8*q;
      float* ro_ = SG + (img*20 + 2*p+1)*264 + 8*q;
      {
        float4 e0 = *(float4*)&re[0];
        float4 e1 = *(float4*)&re[4];
        e0.x -= ue[0]; e0.y -= ue[1]; e0.z -= ue[2]; e0.w -= ue[3];
        e1.x -= ue[4]; e1.y -= ue[5]; e1.z -= ue[6]; e1.w -= ue[7];
        *(float4*)&re[0] = e0; *(float4*)&re[4] = e1;
      }
      {
        float4 o0 = *(float4*)&ro_[0];
        float4 o1 = *(float4*)&ro_[4];
        o0.x -= uo[0]; o0.y -= uo[1]; o0.z -= uo[2]; o0.w -= uo[3];
        o1.x -= uo[4]; o1.y -= uo[5]; o1.z -= uo[6]; o1.w -= uo[7];
        *(float4*)&ro_[0] = o0; *(float4*)&ro_[4] = o1;
      }
    }
    __syncthreads();
    keep = SG[t] + SG[5280 + t];
  } else if (MODE==3){
    float vacc = 0.f;
    for (int k=0; k<1024/NT; k++){
      int u = t + NT*k;
      int img = u & 1;
      int quad = u >> 1;
      int qx = quad & 63;
      int qy = quad >> 6;
      const float* sgb = SG + img*5280;
      int cb = 4*qx, rb = 2*qy;
      float T0[4]={0,0,0,0}, T1[4]={0,0,0,0};
      float s5a[4], s5b[4], s3a[4], s3b[4], n0[4], n1[4];
      #pragma unroll
      for (int r=0;r<6;r++){
        const float* rp = &sgb[(rb+r)*264 + cb];
        float4 t0 = *(const float4*)&rp[0];
        float4 t1 = *(const float4*)&rp[4];
        float4 t2 = *(const float4*)&rp[8];
        float w[12];
        w[0]=t0.x; w[1]=t0.y; w[2]=t0.z;  w[3]=t0.w;
        w[4]=t1.x; w[5]=t1.y; w[6]=t1.z;  w[7]=t1.w;
        w[8]=t2.x; w[9]=t2.y; w[10]=t2.z; w[11]=t2.w;
        float aw[8];
        #pragma unroll
        for (int j=0;j<8;j++) aw[j] = fabsf(w[j+2]);
        float h0 = ((aw[0]+aw[1])+(aw[2]+aw[3]))+aw[4];
        float h1 = h0 - aw[0] + aw[5];
        float h2 = h1 - aw[1] + aw[6];
        float h3 = h2 - aw[2] + aw[7];
        float hh[4] = {h0,h1,h2,h3};
        if (r<=4){
          #pragma unroll
          for (int c=0;c<4;c++) T0[c] += hh[c];
        }
        if (r>=1){
          #pragma unroll
          for (int c=0;c<4;c++) T1[c] += hh[c];
        }
        if (r==0){
          #pragma unroll
          for (int c=0;c<4;c++) s5a[c] = aw[c+2];
        }
        if (r==1){
          #pragma unroll
          for (int c=0;c<4;c++){ s3a[c] = aw[c+1]+aw[c+3]; s5b[c] = aw[c+2]; }
        }
        if (r==2){
          #pragma unroll
          for (int c=0;c<4;c++){ s5a[c] += aw[c]+aw[c+2]+aw[c+4]; n0[c]=w[c+4]; s3b[c] = aw[c+1]+aw[c+3]; }
        }
        if (r==3){
          #pragma unroll
          for (int c=0;c<4;c++){ s3a[c] += aw[c+1]+aw[c+3]; s5b[c] += aw[c]+aw[c+2]+aw[c+4]; n1[c]=w[c+4]; }
        }
        if (r==4){
          #pragma unroll
          for (int c=0;c<4;c++){ s5a[c] += aw[c+2]; s3b[c] += aw[c+1]+aw[c+3]; }
        }
        if (r==5){
          #pragma unroll
          for (int c=0;c<4;c++) s5b[c] += aw[c+2];
        }
      }
      float qv[8];
      #pragma unroll
      for (int c=0;c<4;c++){
        float d0 = SIG0 + 0.04f*T0[c] + 0.01f*s5a[c] - 0.01f*s3a[c];
        float d1 = SIG0 + 0.04f*T1[c] + 0.01f*s5b[c] - 0.01f*s3b[c];
        qv[c]   = __fdividef(n0[c], d0);
        qv[4+c] = __fdividef(n1[c], d1);
      }
      #pragma unroll
      for (int i=0;i<8;i++){
        float o = __shfl_xor(qv[i], 1);
        float d = qv[i] - o;
        vacc += d*d;
      }
    }
    keep = vacc;
  } else {
    keep = SG[t] + SG[5280 + t] + S1L[t];
  }
  #pragma unroll
  for (int off=32; off>0; off>>=1) keep += __shfl_down(keep, off);
  if ((t&63)==0) RED[t>>6] = keep;
  __syncthreads();
  if (t==0){
    float s = 0.f;
    for (int i=0;i<NT/64;i++) s += RED[i];
    dead[(z*32+yt)*2+xt] = s;
  }
}

__global__ __launch_bounds__(256)
void k_dgD(const float* __restrict__ h, const float* __restrict__ l,
           const float* __restrict__ g1, float* __restrict__ dead){
  diag_body<0,256>(h,l,g1,dead);
}
__global__ __launch_bounds__(512)
void k_dgE(const float* __restrict__ h, const float* __restrict__ l,
           const float* __restrict__ g1, float* __restrict__ dead){
  diag_body<0,512>(h,l,g1,dead);
}
__global__ __launch_bounds__(256)
void k_dgA(const float* __restrict__ h, const float* __restrict__ l,
           const float* __restrict__ g1, float* __restrict__ dead){
  diag_body<1,256>(h,l,g1,dead);
}
__global__ __launch_bounds__(256)
void k_dgB(const float* __restrict__ h, const float* __restrict__ l,
           const float* __restrict__ g1, float* __restrict__ dead){
  diag_body<2,256>(h,l,g1,dead);
}
__global__ __launch_bounds__(256)
void k_dgC(const float* __restrict__ h, const float* __restrict__ l,
           const float* __restrict__ g1, float* __restrict__ dead){
  diag_body<3,256>(h,l,g1,dead);
}

extern "C" void kernel_launch(void* const* d_in, const int* in_sizes, int n_in,
                              void* d_out, int out_size, void* d_ws, size_t ws_size,
                              hipStream_t stream){
  const float* h = (const float*)d_in[0];
  const float* l = (const float*)d_in[1];
  float* out = (float*)d_out;
  float* ws = (float*)d_ws;

  float* g1 = ws;                         // 32 * 260*264
  float* g2 = g1 + 2196480;               // 32 * 132*136
  float* g3 = g2 + 574464;                // 32 * 68*72
  float* accum = g3 + 156672;             // 112 ([48..111] written by tail)
  float* p0 = accum + 112;                // 1024
  float* p1 = p0 + 1024;                  // 512
  float* p2s = p1 + 512;                  // 256
  float* dead = p2s + 256;                // 5*1024 diagnostic dead slots

  const size_t ld1  = (20*520 + 20*256)*sizeof(float);
  const size_t lf0  = (2*20*264 + 2*12*136 + 4)*sizeof(float);
  const size_t ldn1 = (20*264 + 20*128)*sizeof(float);
  const size_t lf1  = (2*12*264 + 2*8*136 + 4)*sizeof(float);
  const size_t ldn2 = (20*136 + 20*64)*sizeof(float);
  const size_t lf2  = (2*12*136 + 2*8*72 + 4)*sizeof(float);
  const size_t lfD  = (10560 + 3264 + 8)*sizeof(float);

  k_d1        <<<dim3(32,32),   256, ld1,  stream>>>(h, l, g1);
  k_fused0    <<<dim3(2,32,16), 256, lf0,  stream>>>(h, l, g1, p0);
  k_down<256> <<<dim3(16,32),   256, ldn1, stream>>>(g1, g2);
  k_fused1    <<<dim3(32,16),   256, lf1,  stream>>>(g1, g2, p1);
  k_down<128> <<<dim3(8,32),    256, ldn2, stream>>>(g2, g3);
  k_fused2    <<<dim3(16,16),   256, lf2,  stream>>>(g2, g3, p2s);
  k_tail      <<<16, 256, sizeof(TS), stream>>>(g3, accum);
  k_d6        <<<1, 64, 0, stream>>>(p0, p1, p2s, accum, out);

  // ---- diagnostics (dead writes only) ----
  k_dgD<<<dim3(2,32,16), 256, lfD, stream>>>(h, l, g1, dead + 0);
  k_dgE<<<dim3(2,32,16), 512, lfD, stream>>>(h, l, g1, dead + 1024);
  k_dgA<<<dim3(2,32,16), 256, lfD, stream>>>(h, l, g1, dead + 2048);
  k_dgB<<<dim3(2,32,16), 256, lfD, stream>>>(h, l, g1, dead + 3072);
  k_dgC<<<dim3(2,32,16), 256, lfD, stream>>>(h, l, g1, dead + 4096);
}

// Round 15
// 159.181 us; speedup vs baseline: 2.0195x; 2.0195x over previous
//
#include <hip/hip_runtime.h>

#define SIG0 0.17f
#define SIG1 4.86f

__device__ __constant__ float c_filt0[25] = {
  0.04f,0.04f,0.05f,0.04f,0.04f,
  0.04f,0.03f,0.04f,0.03f,0.04f,
  0.05f,0.04f,0.05f,0.04f,0.05f,
  0.04f,0.03f,0.04f,0.03f,0.04f,
  0.04f,0.04f,0.05f,0.04f,0.04f};
__device__ __constant__ float c_f1d[5] = {0.05f,0.25f,0.4f,0.25f,0.05f};

static __device__ __forceinline__ int iclamp(int v, int lo, int hi){
  return v < lo ? lo : (v > hi ? hi : v);
}

// Padded level buffers: level size S stored as (S+4) rows x (S+8) cols,
// logical (y,x) at [(y+2)*(S+8) + (x+4)], apron = replicate of border.
// g1: S=256 PS=264 (img stride 68640); g2: S=128 PS=136 (17952); g3: S=64 PS=72 (4896)

struct FS {                      // fused kernel: 64x16 output tile
  float sg[2][20][76];
  float s1[2][12][44];
  float red[4];
};
struct DS {                      // down kernel: 64x8 output tile
  float st[20][136];
  float hs[20][64];
};
struct TS {                      // tail kernel
  float A3[2][64][66];
  float A4[2][32][34];
  float A5[2][16][18];
  float A6[2][8][10];
  float red[4];
};

// ================= down body =================
__device__ __forceinline__ void down_body(const float* __restrict__ in0, float* __restrict__ out0,
                                          int PSI, int PSO, int Sout, int xo0, int yo0, char* smem){
  DS* S = (DS*)smem;
  int tid = threadIdx.x;
  for (int f=tid; f<20*34; f+=256){
    int r=f/34, c4=f-34*r;
    *(float4*)&S->st[r][4*c4] = *(const float4*)&in0[(size_t)(2*yo0+r)*PSI + 2*xo0 + 4*c4];
  }
  __syncthreads();
  for (int f=tid; f<20*64; f+=256){
    int r=f>>6, xo=f&63;
    const float* rp = &S->st[r][2*xo+2];
    S->hs[r][xo] = 0.05f*rp[0]+0.25f*rp[1]+0.4f*rp[2]+0.25f*rp[3]+0.05f*rp[4];
  }
  __syncthreads();
  for (int f=tid; f<8*64; f+=256){
    int yo=f>>6, xo=f&63;
    int Y=yo0+yo, X=xo0+xo;
    float v = 0.05f*S->hs[2*yo][xo]+0.25f*S->hs[2*yo+1][xo]+0.4f*S->hs[2*yo+2][xo]
            +0.25f*S->hs[2*yo+3][xo]+0.05f*S->hs[2*yo+4][xo];
    int rlo=(Y==0)?0:(Y+2), rhi=(Y==Sout-1)?(Sout+3):(Y+2);
    int clo=(X==0)?0:(X+4), chi=(X==Sout-1)?(Sout+7):(X+4);
    for (int rr=rlo; rr<=rhi; rr++)
      for (int cc=clo; cc<=chi; cc++)
        out0[(size_t)rr*PSO+cc] = v;
  }
}

// ================= k_d1: gamma + down0 =================
__global__ __launch_bounds__(256)
void k_d1(const float* __restrict__ hin, const float* __restrict__ lin,
          float* __restrict__ g1){
  __shared__ DS S;
  int xo0 = blockIdx.x*64, yo0 = blockIdx.y*8, z = blockIdx.z;
  const float* in = (z<16)? hin + (size_t)z*262144 : lin + (size_t)(z-16)*262144;
  float* out0 = g1 + (size_t)z*68640;
  int tid = threadIdx.x;
  const float e = 0.3846153846153846f;
  for (int f=tid; f<20*34; f+=256){
    int r=f/34, c4=f-34*r;
    int yy = iclamp(2*yo0-2+r, 0, 511);
    int xb = 2*xo0-4+4*c4;
    const float* rp = in + (size_t)yy*512;
    float4 v;
    if (xb>=0 && xb<=508) v = *(const float4*)&rp[xb];
    else { v.x=rp[iclamp(xb,0,511)]; v.y=rp[iclamp(xb+1,0,511)];
           v.z=rp[iclamp(xb+2,0,511)]; v.w=rp[iclamp(xb+3,0,511)]; }
    v.x=__powf(v.x,e); v.y=__powf(v.y,e); v.z=__powf(v.z,e); v.w=__powf(v.w,e);
    *(float4*)&S.st[r][4*c4] = v;
  }
  __syncthreads();
  for (int f=tid; f<20*64; f+=256){
    int r=f>>6, xo=f&63;
    const float* rp = &S.st[r][2*xo+2];
    S.hs[r][xo] = 0.05f*rp[0]+0.25f*rp[1]+0.4f*rp[2]+0.25f*rp[3]+0.05f*rp[4];
  }
  __syncthreads();
  for (int f=tid; f<8*64; f+=256){
    int yo=f>>6, xo=f&63;
    int Y=yo0+yo, X=xo0+xo;
    float v = 0.05f*S.hs[2*yo][xo]+0.25f*S.hs[2*yo+1][xo]+0.4f*S.hs[2*yo+2][xo]
            +0.25f*S.hs[2*yo+3][xo]+0.05f*S.hs[2*yo+4][xo];
    int rlo=(Y==0)?0:(Y+2), rhi=(Y==255)?259:(Y+2);
    int clo=(X==0)?0:(X+4), chi=(X==255)?263:(X+4);
    for (int rr=rlo; rr<=rhi; rr++)
      for (int cc=clo; cc<=chi; cc++)
        out0[(size_t)rr*264+cc] = v;
  }
}

// ================= fused body: lap + replicate-fix + den + diff + reduce =================
template<int GAMMA>
__device__ __forceinline__ void fused_body(FS* S,
    const float* __restrict__ a0, const float* __restrict__ a1, int PS0,
    const float* __restrict__ s10, const float* __restrict__ s11, int PS1,
    int Simg, int x0, int y0, float* __restrict__ out_slot){
  int t = threadIdx.x;
  const float e = 0.3846153846153846f;

  // ---- p1a: stage sg (240 segments of 12 floats) ----
  if (t < 240){
    int img = t >= 120; int t2 = img ? t-120 : t;
    int r = t2/6, q3 = t2 - 6*r;
    float w[12];
    if (GAMMA){
      int yy = iclamp(y0-2+r, 0, 511);
      int xb = x0-4+12*q3;
      const float* rp = (img ? a1 : a0) + (size_t)yy*512;
      if (xb >= 0 && xb <= 500){
        *(float4*)&w[0] = *(const float4*)&rp[xb];
        *(float4*)&w[4] = *(const float4*)&rp[xb+4];
        *(float4*)&w[8] = *(const float4*)&rp[xb+8];
      } else {
        #pragma unroll
        for (int j=0;j<12;j++) w[j] = rp[iclamp(xb+j,0,511)];
      }
      #pragma unroll
      for (int j=0;j<12;j++) w[j] = __powf(w[j], e);
    } else {
      const float* rp = (img ? a1 : a0) + (size_t)(y0+r)*PS0 + x0 + 12*q3;
      *(float4*)&w[0] = *(const float4*)&rp[0];
      *(float4*)&w[4] = *(const float4*)&rp[4];
      *(float4*)&w[8] = *(const float4*)&rp[8];
    }
    float* dp = &S->sg[img][r][12*q3];
    *(float4*)&dp[0] = *(float4*)&w[0];
    *(float4*)&dp[4] = *(float4*)&w[4];
    *(float4*)&dp[8] = *(float4*)&w[8];
  }
  // ---- p1b: stage s1 ----
  if (t < 240){
    int img = t >= 120; int t2 = img ? t-120 : t;
    int ro = t2/10, co = t2 - 10*ro;
    const float* src = (img ? s11 : s10) + (size_t)(y0/2+ro)*PS1 + x0/2 + 4*co;
    *(float4*)&S->s1[img][ro][4*co] = *(const float4*)src;
  }
  __syncthreads();

  // ---- p2: lap in place; thread = (img, row-pair, 8-col segment); branch-free, aligned ----
  if (t < 180){
    int img = t >= 90; int t2 = img ? t-90 : t;
    int rp_ = t2/9, q = t2 - 9*rp_;
    int cb1 = 4*q;
    int cbg = 8*q;
    float A[8], B[8], C[8];
    *(float4*)&A[0] = *(const float4*)&S->s1[img][rp_  ][cb1];
    *(float4*)&A[4] = *(const float4*)&S->s1[img][rp_  ][cb1+4];
    *(float4*)&B[0] = *(const float4*)&S->s1[img][rp_+1][cb1];
    *(float4*)&B[4] = *(const float4*)&S->s1[img][rp_+1][cb1+4];
    *(float4*)&C[0] = *(const float4*)&S->s1[img][rp_+2][cb1];
    *(float4*)&C[4] = *(const float4*)&S->s1[img][rp_+2][cb1+4];
    float ue[8], uo[8];
    #pragma unroll
    for (int j=0;j<4;j++){
      float hEA = 0.05f*A[j+1]+0.4f*A[j+2]+0.05f*A[j+3];
      float hEB = 0.05f*B[j+1]+0.4f*B[j+2]+0.05f*B[j+3];
      float hEC = 0.05f*C[j+1]+0.4f*C[j+2]+0.05f*C[j+3];
      float hOA = 0.25f*(A[j+2]+A[j+3]);
      float hOB = 0.25f*(B[j+2]+B[j+3]);
      float hOC = 0.25f*(C[j+2]+C[j+3]);
      ue[2*j]   = 0.2f*hEA + 1.6f*hEB + 0.2f*hEC;
      ue[2*j+1] = 0.2f*hOA + 1.6f*hOB + 0.2f*hOC;
      uo[2*j]   = hEB + hEC;
      uo[2*j+1] = hOB + hOC;
    }
    float* dpe = &S->sg[img][2*rp_][cbg];
    float ve[8];
    *(float4*)&ve[0]=*(float4*)&dpe[0]; *(float4*)&ve[4]=*(float4*)&dpe[4];
    #pragma unroll
    for (int j=0;j<8;j++) ve[j] -= ue[j];
    *(float4*)&dpe[0]=*(float4*)&ve[0]; *(float4*)&dpe[4]=*(float4*)&ve[4];
    float* dpo = &S->sg[img][2*rp_+1][cbg];
    float vo[8];
    *(float4*)&vo[0]=*(float4*)&dpo[0]; *(float4*)&vo[4]=*(float4*)&dpo[4];
    #pragma unroll
    for (int j=0;j<8;j++) vo[j] -= uo[j];
    *(float4*)&dpo[0]=*(float4*)&vo[0]; *(float4*)&dpo[4]=*(float4*)&vo[4];
  }
  __syncthreads();

  // ---- replicate fix-up on lap tile borders ----
  bool top=(y0==0), bot=(y0+16==Simg), lft=(x0==0), rgt=(x0+64==Simg);
  if (top|bot|lft|rgt){
    for (int f=t; f<2*18; f+=256){
      int img = f>=18; int q = img ? f-18 : f;
      if (top){ float4 v=*(float4*)&S->sg[img][2][4*q];
                *(float4*)&S->sg[img][0][4*q]=v; *(float4*)&S->sg[img][1][4*q]=v; }
      if (bot){ float4 v=*(float4*)&S->sg[img][17][4*q];
                *(float4*)&S->sg[img][18][4*q]=v; *(float4*)&S->sg[img][19][4*q]=v; }
    }
    __syncthreads();
    for (int f=t; f<2*20; f+=256){
      int img = f>=20; int r = img ? f-20 : f;
      if (lft){ float v=S->sg[img][r][4];  float4 vv={v,v,v,v}; *(float4*)&S->sg[img][r][0]=vv; }
      if (rgt){ float v=S->sg[img][r][67]; float4 vv={v,v,v,v}; *(float4*)&S->sg[img][r][68]=vv; }
    }
    __syncthreads();
  }

  // ---- p3: box-trick den conv, 4-wide x 4-tall quads (t<128 active) ----
  // den = SIG0 + 0.04*T + 0.01*s05 - 0.01*s03
  float vacc = 0.f;
  if (t < 128){
    int img = t & 1, quad = t >> 1;        // quad 0..63
    int qx = quad & 15, qy = quad >> 4;    // qx 0..15, qy 0..3
    int cb = 4*qx, rb = 4*qy;
    float T[4][4], s5[4][4], s3[4][4], n[4][4];
    #pragma unroll
    for (int o=0;o<4;o++){
      #pragma unroll
      for (int c=0;c<4;c++){ T[o][c]=0.f; s5[o][c]=0.f; s3[o][c]=0.f; }
    }
    #pragma unroll
    for (int r=0;r<8;r++){
      const float* rp = &S->sg[img][rb+r][cb];
      float4 t0 = *(const float4*)&rp[0];
      float4 t1 = *(const float4*)&rp[4];
      float4 t2 = *(const float4*)&rp[8];
      float w[12];
      w[0]=t0.x; w[1]=t0.y; w[2]=t0.z;  w[3]=t0.w;
      w[4]=t1.x; w[5]=t1.y; w[6]=t1.z;  w[7]=t1.w;
      w[8]=t2.x; w[9]=t2.y; w[10]=t2.z; w[11]=t2.w;
      float aw[8];
      #pragma unroll
      for (int j=0;j<8;j++) aw[j] = fabsf(w[j+2]);
      float h0 = ((aw[0]+aw[1])+(aw[2]+aw[3]))+aw[4];
      float h1 = h0 - aw[0] + aw[5];
      float h2 = h1 - aw[1] + aw[6];
      float h3 = h2 - aw[2] + aw[7];
      float hh[4] = {h0,h1,h2,h3};
      #pragma unroll
      for (int o=0;o<4;o++){
        if (r>=o && r<=o+4){
          #pragma unroll
          for (int c=0;c<4;c++) T[o][c] += hh[c];
        }
        if (r==o || r==o+4){
          #pragma unroll
          for (int c=0;c<4;c++) s5[o][c] += aw[c+2];
        }
        if (r==o+2){
          #pragma unroll
          for (int c=0;c<4;c++){ s5[o][c] += aw[c]+aw[c+2]+aw[c+4]; n[o][c] = w[c+4]; }
        }
        if (r==o+1 || r==o+3){
          #pragma unroll
          for (int c=0;c<4;c++) s3[o][c] += aw[c+1]+aw[c+3];
        }
      }
    }
    #pragma unroll
    for (int o=0;o<4;o++){
      #pragma unroll
      for (int c=0;c<4;c++){
        float den = SIG0 + 0.04f*T[o][c] + 0.01f*s5[o][c] - 0.01f*s3[o][c];
        float qv = __fdividef(n[o][c], den);
        float other = __shfl_xor(qv, 1);
        float d = qv - other;
        vacc += d*d;
      }
    }
    if (img) vacc = 0.f;   // count each pair once
  }
  #pragma unroll
  for (int off=32; off>0; off>>=1) vacc += __shfl_down(vacc, off);
  if ((t&63)==0) S->red[t>>6] = vacc;
  __syncthreads();
  if (t==0)
    out_slot[0] = S->red[0]+S->red[1]+S->red[2]+S->red[3];
}

// ================= tail (levels 3..6) helpers =================
static __device__ __forceinline__ void down_lds(const float* Ain, int ldi, int Sin,
                                                float* Aout, int ldo, int Sout,
                                                int tid, int NT){
  int tot = 2*Sout*Sout;
  for (int f=tid; f<tot; f+=NT){
    int img = f/(Sout*Sout), rem = f%(Sout*Sout), y=rem/Sout, x=rem%Sout;
    const float* A = Ain + img*Sin*ldi;
    float s=0.f;
    #pragma unroll
    for (int i=0;i<5;i++){
      int yy=iclamp(2*y+i-2,0,Sin-1);
      float rs=0.f;
      #pragma unroll
      for (int j=0;j<5;j++){
        int xx=iclamp(2*x+j-2,0,Sin-1);
        rs += c_f1d[j]*A[yy*ldi+xx];
      }
      s += c_f1d[i]*rs;
    }
    Aout[img*Sout*ldo + y*ldo + x] = s;
  }
}

static __device__ __forceinline__ void lap_lds(float* Ak, int ldk, int S,
                                               const float* Ag, int ldg,
                                               int tid, int NT){
  int Sg = S>>1;
  int tot = 2*S*S;
  for (int f=tid; f<tot; f+=NT){
    int img=f/(S*S), rem=f%(S*S), y=rem/S, x=rem%S;
    const float* G = Ag + img*Sg*ldg;
    int y2=y>>1, x2=x>>1;
    int ry0,ry1,ry2; float wy0,wy1,wy2;
    if (!(y&1)){ ry0=iclamp(y2-1,0,Sg-1); ry1=y2; ry2=iclamp(y2+1,0,Sg-1); wy0=0.2f; wy1=1.6f; wy2=0.2f; }
    else { ry0=y2; ry1=iclamp(y2+1,0,Sg-1); ry2=y2; wy0=1.f; wy1=1.f; wy2=0.f; }
    int cx0,cx1,cx2; float wx0,wx1,wx2;
    if (!(x&1)){ cx0=iclamp(x2-1,0,Sg-1); cx1=x2; cx2=iclamp(x2+1,0,Sg-1); wx0=0.05f; wx1=0.4f; wx2=0.05f; }
    else { cx0=x2; cx1=iclamp(x2+1,0,Sg-1); cx2=x2; wx0=0.25f; wx1=0.25f; wx2=0.f; }
    float u0 = wx0*G[ry0*ldg+cx0]+wx1*G[ry0*ldg+cx1]+wx2*G[ry0*ldg+cx2];
    float u1 = wx0*G[ry1*ldg+cx0]+wx1*G[ry1*ldg+cx1]+wx2*G[ry1*ldg+cx2];
    float u2 = wx0*G[ry2*ldg+cx0]+wx1*G[ry2*ldg+cx1]+wx2*G[ry2*ldg+cx2];
    Ak[img*S*ldk + y*ldk + x] -= wy0*u0+wy1*u1+wy2*u2;
  }
}

static __device__ __forceinline__ float diff_lds(const float* A, int ld, int S,
                                                 int tid, int NT){
  float v=0.f;
  const float* Ah = A;
  const float* Al = A + S*ld;
  for (int f=tid; f<S*S; f+=NT){
    int y=f/S, x=f%S;
    float dh=SIG0, dl=SIG0;
    #pragma unroll
    for (int i=0;i<5;i++){
      int yy=iclamp(y+i-2,0,S-1);
      #pragma unroll
      for (int j=0;j<5;j++){
        int xx=iclamp(x+j-2,0,S-1);
        float w=c_filt0[i*5+j];
        dh += w*fabsf(Ah[yy*ld+xx]);
        dl += w*fabsf(Al[yy*ld+xx]);
      }
    }
    float d = __fdividef(Ah[y*ld+x],dh) - __fdividef(Al[y*ld+x],dl);
    v += d*d;
  }
  return v;
}

__device__ void tail_body(const float* __restrict__ g3, float* __restrict__ accum,
                          int b, char* smem){
  TS* T = (TS*)smem;
  int tid = threadIdx.x;
  const float* s0  = g3 + (size_t)b*4896 + 148;
  const float* s1p = g3 + (size_t)(b+16)*4896 + 148;
  for (int f=tid; f<2*4096; f+=256){
    int img=f>>12, rem=f&4095, r=rem>>6, c=rem&63;
    T->A3[img][r][c] = (img? s1p : s0)[(size_t)r*72+c];
  }
  __syncthreads();
  down_lds(&T->A3[0][0][0],66,64,&T->A4[0][0][0],34,32,tid,256);
  __syncthreads();
  down_lds(&T->A4[0][0][0],34,32,&T->A5[0][0][0],18,16,tid,256);
  __syncthreads();
  down_lds(&T->A5[0][0][0],18,16,&T->A6[0][0][0],10,8,tid,256);
  __syncthreads();
  lap_lds(&T->A3[0][0][0],66,64,&T->A4[0][0][0],34,tid,256);
  __syncthreads();
  float v3 = diff_lds(&T->A3[0][0][0],66,64,tid,256);
  lap_lds(&T->A4[0][0][0],34,32,&T->A5[0][0][0],18,tid,256);
  __syncthreads();
  float v4 = diff_lds(&T->A4[0][0][0],34,32,tid,256);
  lap_lds(&T->A5[0][0][0],18,16,&T->A6[0][0][0],10,tid,256);
  __syncthreads();
  float v5 = diff_lds(&T->A5[0][0][0],18,16,tid,256);
  float v6 = 0.f;
  for (int f=tid; f<64; f+=256){
    float ch = T->A6[0][f>>3][f&7];
    float cl = T->A6[1][f>>3][f&7];
    float d = __fdividef(ch, fabsf(ch)+SIG1) - __fdividef(cl, fabsf(cl)+SIG1);
    v6 += d*d;
  }
  float vs[4] = {v3, v4, v5, v6};
  #pragma unroll
  for (int k=0;k<4;k++){
    float v = vs[k];
    #pragma unroll
    for (int off=32; off>0; off>>=1) v += __shfl_down(v, off);
    if ((tid&63)==0) T->red[tid>>6] = v;
    __syncthreads();
    if (tid==0)
      accum[(3+k)*16 + b] = T->red[0]+T->red[1]+T->red[2]+T->red[3];
    __syncthreads();
  }
}

// ================= dispatch kernels =================
__global__ __launch_bounds__(256)
void k_d2(const float* __restrict__ h, const float* __restrict__ l,
          const float* __restrict__ g1, float* __restrict__ g2,
          float* __restrict__ p0){
  extern __shared__ char smem[];
  if (blockIdx.z < 16){
    int b = blockIdx.z, x0 = blockIdx.x*64, y0 = blockIdx.y*16;
    fused_body<1>((FS*)smem, h+(size_t)b*262144, l+(size_t)b*262144, 0,
                  g1+(size_t)b*68640, g1+(size_t)(b+16)*68640, 264,
                  512, x0, y0, p0 + b*256 + blockIdx.y*8 + blockIdx.x);
  } else {
    int id = (blockIdx.z-16)*256 + blockIdx.y*8 + blockIdx.x;
    int img = id>>5, rem = id&31, xt = rem&1, yt = rem>>1;
    down_body(g1+(size_t)img*68640, g2+(size_t)img*17952, 264, 136, 128, xt*64, yt*8, smem);
  }
}

__global__ __launch_bounds__(256)
void k_d4(const float* __restrict__ g1, float* __restrict__ g2,
          float* __restrict__ g3, float* __restrict__ p1){
  extern __shared__ char smem[];
  if (blockIdx.z < 16){
    int b = blockIdx.z, x0 = blockIdx.x*64, y0 = blockIdx.y*16;
    fused_body<0>((FS*)smem, g1+(size_t)b*68640, g1+(size_t)(b+16)*68640, 264,
                  g2+(size_t)b*17952, g2+(size_t)(b+16)*17952, 136,
                  256, x0, y0, p1 + b*64 + blockIdx.y*4 + blockIdx.x);
  } else {
    int id = (blockIdx.z-16)*64 + blockIdx.y*4 + blockIdx.x;
    int img = id>>3, yt = id&7;
    down_body(g2+(size_t)img*17952, g3+(size_t)img*4896, 136, 72, 64, 0, yt*8, smem);
  }
}

__global__ __launch_bounds__(256)
void k_d5(const float* __restrict__ g2, const float* __restrict__ g3,
          float* __restrict__ p2, float* __restrict__ accum){
  extern __shared__ char smem[];
  if (blockIdx.z < 16){
    int b = blockIdx.z, x0 = blockIdx.x*64, y0 = blockIdx.y*16;
    fused_body<0>((FS*)smem, g2+(size_t)b*17952, g2+(size_t)(b+16)*17952, 136,
                  g3+(size_t)b*4896, g3+(size_t)(b+16)*4896, 72,
                  128, x0, y0, p2 + b*16 + blockIdx.y*2 + blockIdx.x);
  } else {
    int id = blockIdx.y*2 + blockIdx.x;
    tail_body(g3, accum, id, smem);
  }
}

// ================= finalize: reduce partials + formula =================
__global__ __launch_bounds__(256)
void k_d6(const float* __restrict__ p0, const float* __restrict__ p1,
          const float* __restrict__ p2, const float* __restrict__ accum,
          float* __restrict__ out){
  __shared__ float r0[16][16];
  __shared__ float r1[16][4];
  __shared__ float r2[16];
  __shared__ float fin[16];
  int t = threadIdx.x;
  {
    int b = t>>4, c = t&15;
    float s = 0.f;
    #pragma unroll
    for (int j=0;j<16;j++) s += p0[b*256 + c*16 + j];
    r0[b][c] = s;
  }
  if (t < 64){
    int b = t>>2, c = t&3;
    float s = 0.f;
    #pragma unroll
    for (int j=0;j<16;j++) s += p1[b*64 + c*16 + j];
    r1[b][c] = s;
  }
  if (t < 16){
    float s = 0.f;
    #pragma unroll
    for (int j=0;j<16;j++) s += p2[t*16 + j];
    r2[t] = s;
  }
  __syncthreads();
  if (t < 16){
    int b = t;
    float a0 = 0.f;
    #pragma unroll
    for (int c=0;c<16;c++) a0 += r0[b][c];
    float a1 = (r1[b][0]+r1[b][1])+(r1[b][2]+r1[b][3]);
    float a2 = r2[b];
    float m = powf(a0*(1.0f/262144.0f), 0.3f)
            + powf(a1*(1.0f/65536.0f), 0.3f)
            + powf(a2*(1.0f/16384.0f), 0.3f);
    #pragma unroll
    for (int k=3;k<7;k++){
      int hw = (512>>k)*(512>>k);
      m += powf(accum[k*16+b]/(float)hw, 0.3f);
    }
    m *= (1.0f/7.0f);
    fin[b] = powf(m, 1.6666666666666667f);
  }
  __syncthreads();
  if (t == 0){
    float s = 0.f;
    #pragma unroll
    for (int i=0;i<16;i++) s += fin[i];
    out[0] = s * (1.0f/16.0f);
  }
}

extern "C" void kernel_launch(void* const* d_in, const int* in_sizes, int n_in,
                              void* d_out, int out_size, void* d_ws, size_t ws_size,
                              hipStream_t stream){
  const float* h = (const float*)d_in[0];
  const float* l = (const float*)d_in[1];
  float* out = (float*)d_out;
  float* ws = (float*)d_ws;

  float* g1 = ws;                         // 32 * 260*264
  float* g2 = g1 + 2196480;               // 32 * 132*136
  float* g3 = g2 + 574464;                // 32 * 68*72
  float* accum = g3 + 156672;             // 112 ([48..111] written by tail)
  float* p0 = accum + 112;                // 4096 level-0 block partials
  float* p1 = p0 + 4096;                  // 1024 level-1 block partials
  float* p2 = p1 + 1024;                  // 256  level-2 block partials

  size_t fsz = sizeof(FS) > sizeof(DS) ? sizeof(FS) : sizeof(DS);
  size_t tsz = sizeof(TS);

  k_d1<<<dim3(4,32,32), 256, 0, stream>>>(h, l, g1);
  k_d2<<<dim3(8,32,20), 256, fsz, stream>>>(h, l, g1, g2, p0);
  k_d4<<<dim3(4,16,20), 256, fsz, stream>>>(g1, g2, g3, p1);
  k_d5<<<dim3(2,8,17),  256, tsz, stream>>>(g2, g3, p2, accum);
  k_d6<<<1, 256, 0, stream>>>(p0, p1, p2, accum, out);
}

// Round 16
// 158.045 us; speedup vs baseline: 2.0340x; 1.0072x over previous
//
#include <hip/hip_runtime.h>

#define SIG0 0.17f
#define SIG1 4.86f

__device__ __constant__ float c_filt0[25] = {
  0.04f,0.04f,0.05f,0.04f,0.04f,
  0.04f,0.03f,0.04f,0.03f,0.04f,
  0.05f,0.04f,0.05f,0.04f,0.05f,
  0.04f,0.03f,0.04f,0.03f,0.04f,
  0.04f,0.04f,0.05f,0.04f,0.04f};
__device__ __constant__ float c_f1d[5] = {0.05f,0.25f,0.4f,0.25f,0.05f};

static __device__ __forceinline__ int iclamp(int v, int lo, int hi){
  return v < lo ? lo : (v > hi ? hi : v);
}

// Padded level buffers: level size S stored as (S+4) rows x (S+8) cols,
// logical (y,x) at [(y+2)*(S+8) + (x+4)], apron = replicate of border.
// g1: S=256 PS=264 (img stride 68640); g2: S=128 PS=136 (17952); g3: S=64 PS=72 (4896)

struct FS {                      // fused kernel: 64x16 output tile
  float sg[2][20][76];
  float s1[2][12][44];
  float red[4];
};
struct DS {                      // down kernel: 64x8 output tile
  float st[20][136];
  float hs[20][64];
};
struct TS {                      // tail kernel
  float A3[2][64][66];
  float A4[2][32][34];
  float A5[2][16][18];
  float A6[2][8][10];
  float red[4];
};

// ================= down body =================
__device__ __forceinline__ void down_body(const float* __restrict__ in0, float* __restrict__ out0,
                                          int PSI, int PSO, int Sout, int xo0, int yo0, char* smem){
  DS* S = (DS*)smem;
  int tid = threadIdx.x;
  for (int f=tid; f<20*34; f+=256){
    int r=f/34, c4=f-34*r;
    *(float4*)&S->st[r][4*c4] = *(const float4*)&in0[(size_t)(2*yo0+r)*PSI + 2*xo0 + 4*c4];
  }
  __syncthreads();
  for (int f=tid; f<20*64; f+=256){
    int r=f>>6, xo=f&63;
    const float* rp = &S->st[r][2*xo+2];
    S->hs[r][xo] = 0.05f*rp[0]+0.25f*rp[1]+0.4f*rp[2]+0.25f*rp[3]+0.05f*rp[4];
  }
  __syncthreads();
  for (int f=tid; f<8*64; f+=256){
    int yo=f>>6, xo=f&63;
    int Y=yo0+yo, X=xo0+xo;
    float v = 0.05f*S->hs[2*yo][xo]+0.25f*S->hs[2*yo+1][xo]+0.4f*S->hs[2*yo+2][xo]
            +0.25f*S->hs[2*yo+3][xo]+0.05f*S->hs[2*yo+4][xo];
    int rlo=(Y==0)?0:(Y+2), rhi=(Y==Sout-1)?(Sout+3):(Y+2);
    int clo=(X==0)?0:(X+4), chi=(X==Sout-1)?(Sout+7):(X+4);
    for (int rr=rlo; rr<=rhi; rr++)
      for (int cc=clo; cc<=chi; cc++)
        out0[(size_t)rr*PSO+cc] = v;
  }
}

// ================= k_d1: gamma + down0 =================
__global__ __launch_bounds__(256)
void k_d1(const float* __restrict__ hin, const float* __restrict__ lin,
          float* __restrict__ g1){
  __shared__ DS S;
  int xo0 = blockIdx.x*64, yo0 = blockIdx.y*8, z = blockIdx.z;
  const float* in = (z<16)? hin + (size_t)z*262144 : lin + (size_t)(z-16)*262144;
  float* out0 = g1 + (size_t)z*68640;
  int tid = threadIdx.x;
  const float e = 0.3846153846153846f;
  for (int f=tid; f<20*34; f+=256){
    int r=f/34, c4=f-34*r;
    int yy = iclamp(2*yo0-2+r, 0, 511);
    int xb = 2*xo0-4+4*c4;
    const float* rp = in + (size_t)yy*512;
    float4 v;
    if (xb>=0 && xb<=508) v = *(const float4*)&rp[xb];
    else { v.x=rp[iclamp(xb,0,511)]; v.y=rp[iclamp(xb+1,0,511)];
           v.z=rp[iclamp(xb+2,0,511)]; v.w=rp[iclamp(xb+3,0,511)]; }
    v.x=__powf(v.x,e); v.y=__powf(v.y,e); v.z=__powf(v.z,e); v.w=__powf(v.w,e);
    *(float4*)&S.st[r][4*c4] = v;
  }
  __syncthreads();
  for (int f=tid; f<20*64; f+=256){
    int r=f>>6, xo=f&63;
    const float* rp = &S.st[r][2*xo+2];
    S.hs[r][xo] = 0.05f*rp[0]+0.25f*rp[1]+0.4f*rp[2]+0.25f*rp[3]+0.05f*rp[4];
  }
  __syncthreads();
  for (int f=tid; f<8*64; f+=256){
    int yo=f>>6, xo=f&63;
    int Y=yo0+yo, X=xo0+xo;
    float v = 0.05f*S.hs[2*yo][xo]+0.25f*S.hs[2*yo+1][xo]+0.4f*S.hs[2*yo+2][xo]
            +0.25f*S.hs[2*yo+3][xo]+0.05f*S.hs[2*yo+4][xo];
    int rlo=(Y==0)?0:(Y+2), rhi=(Y==255)?259:(Y+2);
    int clo=(X==0)?0:(X+4), chi=(X==255)?263:(X+4);
    for (int rr=rlo; rr<=rhi; rr++)
      for (int cc=clo; cc<=chi; cc++)
        out0[(size_t)rr*264+cc] = v;
  }
}

// ================= fused body: lap + replicate-fix + den + diff + reduce =================
// FULLY SCALARIZED: no local arrays anywhere (scratch/alloca avoidance).
template<int GAMMA>
__device__ __forceinline__ void fused_body(FS* S,
    const float* __restrict__ a0, const float* __restrict__ a1, int PS0,
    const float* __restrict__ s10, const float* __restrict__ s11, int PS1,
    int Simg, int x0, int y0, float* __restrict__ out_slot){
  int t = threadIdx.x;
  const float e = 0.3846153846153846f;

  // ---- p1a: stage sg (240 segments of 12 floats) ----
  if (t < 240){
    int img = t >= 120; int t2 = img ? t-120 : t;
    int r = t2/6, q3 = t2 - 6*r;
    float4 w0, w1, w2;
    if (GAMMA){
      int yy = iclamp(y0-2+r, 0, 511);
      int xb = x0-4+12*q3;
      const float* rp = (img ? a1 : a0) + (size_t)yy*512;
      if (xb >= 0 && xb <= 500){
        w0 = *(const float4*)&rp[xb];
        w1 = *(const float4*)&rp[xb+4];
        w2 = *(const float4*)&rp[xb+8];
      } else {
        w0.x=rp[iclamp(xb+0,0,511)];  w0.y=rp[iclamp(xb+1,0,511)];
        w0.z=rp[iclamp(xb+2,0,511)];  w0.w=rp[iclamp(xb+3,0,511)];
        w1.x=rp[iclamp(xb+4,0,511)];  w1.y=rp[iclamp(xb+5,0,511)];
        w1.z=rp[iclamp(xb+6,0,511)];  w1.w=rp[iclamp(xb+7,0,511)];
        w2.x=rp[iclamp(xb+8,0,511)];  w2.y=rp[iclamp(xb+9,0,511)];
        w2.z=rp[iclamp(xb+10,0,511)]; w2.w=rp[iclamp(xb+11,0,511)];
      }
      w0.x=__powf(w0.x,e); w0.y=__powf(w0.y,e); w0.z=__powf(w0.z,e); w0.w=__powf(w0.w,e);
      w1.x=__powf(w1.x,e); w1.y=__powf(w1.y,e); w1.z=__powf(w1.z,e); w1.w=__powf(w1.w,e);
      w2.x=__powf(w2.x,e); w2.y=__powf(w2.y,e); w2.z=__powf(w2.z,e); w2.w=__powf(w2.w,e);
    } else {
      const float* rp = (img ? a1 : a0) + (size_t)(y0+r)*PS0 + x0 + 12*q3;
      w0 = *(const float4*)&rp[0];
      w1 = *(const float4*)&rp[4];
      w2 = *(const float4*)&rp[8];
    }
    float* dp = &S->sg[img][r][12*q3];
    *(float4*)&dp[0] = w0;
    *(float4*)&dp[4] = w1;
    *(float4*)&dp[8] = w2;
  }
  // ---- p1b: stage s1 ----
  if (t < 240){
    int img = t >= 120; int t2 = img ? t-120 : t;
    int ro = t2/10, co = t2 - 10*ro;
    const float* src = (img ? s11 : s10) + (size_t)(y0/2+ro)*PS1 + x0/2 + 4*co;
    *(float4*)&S->s1[img][ro][4*co] = *(const float4*)src;
  }
  __syncthreads();

  // ---- p2: lap in place; thread = (img, row-pair, 8-col segment); scalarized ----
  if (t < 180){
    int img = t >= 90; int t2 = img ? t-90 : t;
    int rp_ = t2/9, q = t2 - 9*rp_;
    int cb1 = 4*q, cbg = 8*q;
    float4 Aa = *(const float4*)&S->s1[img][rp_  ][cb1];
    float4 Ab = *(const float4*)&S->s1[img][rp_  ][cb1+4];
    float4 Ba = *(const float4*)&S->s1[img][rp_+1][cb1];
    float4 Bb = *(const float4*)&S->s1[img][rp_+1][cb1+4];
    float4 Ca = *(const float4*)&S->s1[img][rp_+2][cb1];
    float4 Cb = *(const float4*)&S->s1[img][rp_+2][cb1+4];
    // horizontal taps per j (j=0..3): E = .05*[j+1]+.4*[j+2]+.05*[j+3]; O = .25*([j+2]+[j+3])
    float hEA0=0.05f*Aa.y+0.4f*Aa.z+0.05f*Aa.w, hOA0=0.25f*(Aa.z+Aa.w);
    float hEA1=0.05f*Aa.z+0.4f*Aa.w+0.05f*Ab.x, hOA1=0.25f*(Aa.w+Ab.x);
    float hEA2=0.05f*Aa.w+0.4f*Ab.x+0.05f*Ab.y, hOA2=0.25f*(Ab.x+Ab.y);
    float hEA3=0.05f*Ab.x+0.4f*Ab.y+0.05f*Ab.z, hOA3=0.25f*(Ab.y+Ab.z);
    float hEB0=0.05f*Ba.y+0.4f*Ba.z+0.05f*Ba.w, hOB0=0.25f*(Ba.z+Ba.w);
    float hEB1=0.05f*Ba.z+0.4f*Ba.w+0.05f*Bb.x, hOB1=0.25f*(Ba.w+Bb.x);
    float hEB2=0.05f*Ba.w+0.4f*Bb.x+0.05f*Bb.y, hOB2=0.25f*(Bb.x+Bb.y);
    float hEB3=0.05f*Bb.x+0.4f*Bb.y+0.05f*Bb.z, hOB3=0.25f*(Bb.y+Bb.z);
    float hEC0=0.05f*Ca.y+0.4f*Ca.z+0.05f*Ca.w, hOC0=0.25f*(Ca.z+Ca.w);
    float hEC1=0.05f*Ca.z+0.4f*Ca.w+0.05f*Cb.x, hOC1=0.25f*(Ca.w+Cb.x);
    float hEC2=0.05f*Ca.w+0.4f*Cb.x+0.05f*Cb.y, hOC2=0.25f*(Cb.x+Cb.y);
    float hEC3=0.05f*Cb.x+0.4f*Cb.y+0.05f*Cb.z, hOC3=0.25f*(Cb.y+Cb.z);
    float4 ue0, ue1, uo0, uo1;
    ue0.x=0.2f*hEA0+1.6f*hEB0+0.2f*hEC0;  ue0.y=0.2f*hOA0+1.6f*hOB0+0.2f*hOC0;
    ue0.z=0.2f*hEA1+1.6f*hEB1+0.2f*hEC1;  ue0.w=0.2f*hOA1+1.6f*hOB1+0.2f*hOC1;
    ue1.x=0.2f*hEA2+1.6f*hEB2+0.2f*hEC2;  ue1.y=0.2f*hOA2+1.6f*hOB2+0.2f*hOC2;
    ue1.z=0.2f*hEA3+1.6f*hEB3+0.2f*hEC3;  ue1.w=0.2f*hOA3+1.6f*hOB3+0.2f*hOC3;
    uo0.x=hEB0+hEC0;  uo0.y=hOB0+hOC0;  uo0.z=hEB1+hEC1;  uo0.w=hOB1+hOC1;
    uo1.x=hEB2+hEC2;  uo1.y=hOB2+hOC2;  uo1.z=hEB3+hEC3;  uo1.w=hOB3+hOC3;
    float* dpe = &S->sg[img][2*rp_][cbg];
    float4 v0 = *(float4*)&dpe[0];
    float4 v1 = *(float4*)&dpe[4];
    v0.x-=ue0.x; v0.y-=ue0.y; v0.z-=ue0.z; v0.w-=ue0.w;
    v1.x-=ue1.x; v1.y-=ue1.y; v1.z-=ue1.z; v1.w-=ue1.w;
    *(float4*)&dpe[0] = v0; *(float4*)&dpe[4] = v1;
    float* dpo = &S->sg[img][2*rp_+1][cbg];
    float4 u0 = *(float4*)&dpo[0];
    float4 u1 = *(float4*)&dpo[4];
    u0.x-=uo0.x; u0.y-=uo0.y; u0.z-=uo0.z; u0.w-=uo0.w;
    u1.x-=uo1.x; u1.y-=uo1.y; u1.z-=uo1.z; u1.w-=uo1.w;
    *(float4*)&dpo[0] = u0; *(float4*)&dpo[4] = u1;
  }
  __syncthreads();

  // ---- replicate fix-up on lap tile borders ----
  bool top=(y0==0), bot=(y0+16==Simg), lft=(x0==0), rgt=(x0+64==Simg);
  if (top|bot|lft|rgt){
    for (int f=t; f<2*18; f+=256){
      int img = f>=18; int q = img ? f-18 : f;
      if (top){ float4 v=*(float4*)&S->sg[img][2][4*q];
                *(float4*)&S->sg[img][0][4*q]=v; *(float4*)&S->sg[img][1][4*q]=v; }
      if (bot){ float4 v=*(float4*)&S->sg[img][17][4*q];
                *(float4*)&S->sg[img][18][4*q]=v; *(float4*)&S->sg[img][19][4*q]=v; }
    }
    __syncthreads();
    for (int f=t; f<2*20; f+=256){
      int img = f>=20; int r = img ? f-20 : f;
      if (lft){ float v=S->sg[img][r][4];  float4 vv={v,v,v,v}; *(float4*)&S->sg[img][r][0]=vv; }
      if (rgt){ float v=S->sg[img][r][67]; float4 vv={v,v,v,v}; *(float4*)&S->sg[img][r][68]=vv; }
    }
    __syncthreads();
  }

  // ---- p3: box-trick den conv, 2-row quads, all 256 threads; scalarized ----
  // den = SIG0 + 0.04*T + 0.01*s05 - 0.01*s03
  float vacc = 0.f;
  {
    int img = t & 1, quad = t >> 1;
    int qx = quad & 15, qy = quad >> 4;   // qx 0..15, qy 0..7
    int cb = 4*qx, rb = 2*qy;
    float4 Tq0={0,0,0,0}, Tq1={0,0,0,0};
    float4 s5a={0,0,0,0}, s5b={0,0,0,0}, s3a={0,0,0,0}, s3b={0,0,0,0};
    float4 n0={0,0,0,0}, n1={0,0,0,0};
    #pragma unroll
    for (int r=0;r<6;r++){
      const float* rp = &S->sg[img][rb+r][cb];
      float4 t0 = *(const float4*)&rp[0];
      float4 t1 = *(const float4*)&rp[4];
      float4 t2 = *(const float4*)&rp[8];
      float aw0=fabsf(t0.z), aw1=fabsf(t0.w), aw2=fabsf(t1.x), aw3=fabsf(t1.y);
      float aw4=fabsf(t1.z), aw5=fabsf(t1.w), aw6=fabsf(t2.x), aw7=fabsf(t2.y);
      float h0 = ((aw0+aw1)+(aw2+aw3))+aw4;
      float h1 = h0 - aw0 + aw5;
      float h2 = h1 - aw1 + aw6;
      float h3 = h2 - aw2 + aw7;
      if (r<=4){ Tq0.x+=h0; Tq0.y+=h1; Tq0.z+=h2; Tq0.w+=h3; }
      if (r>=1){ Tq1.x+=h0; Tq1.y+=h1; Tq1.z+=h2; Tq1.w+=h3; }
      if (r==0){ s5a.x=aw2; s5a.y=aw3; s5a.z=aw4; s5a.w=aw5; }
      if (r==1){
        s3a.x=aw1+aw3; s3a.y=aw2+aw4; s3a.z=aw3+aw5; s3a.w=aw4+aw6;
        s5b.x=aw2; s5b.y=aw3; s5b.z=aw4; s5b.w=aw5;
      }
      if (r==2){
        s5a.x+=aw0+aw2+aw4; s5a.y+=aw1+aw3+aw5; s5a.z+=aw2+aw4+aw6; s5a.w+=aw3+aw5+aw7;
        n0 = t1;
        s3b.x=aw1+aw3; s3b.y=aw2+aw4; s3b.z=aw3+aw5; s3b.w=aw4+aw6;
      }
      if (r==3){
        s3a.x+=aw1+aw3; s3a.y+=aw2+aw4; s3a.z+=aw3+aw5; s3a.w+=aw4+aw6;
        s5b.x+=aw0+aw2+aw4; s5b.y+=aw1+aw3+aw5; s5b.z+=aw2+aw4+aw6; s5b.w+=aw3+aw5+aw7;
        n1 = t1;
      }
      if (r==4){
        s5a.x+=aw2; s5a.y+=aw3; s5a.z+=aw4; s5a.w+=aw5;
        s3b.x+=aw1+aw3; s3b.y+=aw2+aw4; s3b.z+=aw3+aw5; s3b.w+=aw4+aw6;
      }
      if (r==5){ s5b.x+=aw2; s5b.y+=aw3; s5b.z+=aw4; s5b.w+=aw5; }
    }
    float q0 = __fdividef(n0.x, SIG0 + 0.04f*Tq0.x + 0.01f*s5a.x - 0.01f*s3a.x);
    float q1 = __fdividef(n0.y, SIG0 + 0.04f*Tq0.y + 0.01f*s5a.y - 0.01f*s3a.y);
    float q2 = __fdividef(n0.z, SIG0 + 0.04f*Tq0.z + 0.01f*s5a.z - 0.01f*s3a.z);
    float q3v= __fdividef(n0.w, SIG0 + 0.04f*Tq0.w + 0.01f*s5a.w - 0.01f*s3a.w);
    float q4 = __fdividef(n1.x, SIG0 + 0.04f*Tq1.x + 0.01f*s5b.x - 0.01f*s3b.x);
    float q5 = __fdividef(n1.y, SIG0 + 0.04f*Tq1.y + 0.01f*s5b.y - 0.01f*s3b.y);
    float q6 = __fdividef(n1.z, SIG0 + 0.04f*Tq1.z + 0.01f*s5b.z - 0.01f*s3b.z);
    float q7 = __fdividef(n1.w, SIG0 + 0.04f*Tq1.w + 0.01f*s5b.w - 0.01f*s3b.w);
    float d0 = q0 - __shfl_xor(q0, 1);
    float d1 = q1 - __shfl_xor(q1, 1);
    float d2 = q2 - __shfl_xor(q2, 1);
    float d3 = q3v- __shfl_xor(q3v, 1);
    float d4 = q4 - __shfl_xor(q4, 1);
    float d5 = q5 - __shfl_xor(q5, 1);
    float d6 = q6 - __shfl_xor(q6, 1);
    float d7 = q7 - __shfl_xor(q7, 1);
    vacc = ((d0*d0+d1*d1)+(d2*d2+d3*d3)) + ((d4*d4+d5*d5)+(d6*d6+d7*d7));
    if (t & 1) vacc = 0.f;   // count each pair once
  }
  #pragma unroll
  for (int off=32; off>0; off>>=1) vacc += __shfl_down(vacc, off);
  if ((t&63)==0) S->red[t>>6] = vacc;
  __syncthreads();
  if (t==0)
    out_slot[0] = S->red[0]+S->red[1]+S->red[2]+S->red[3];
}

// ================= tail (levels 3..6) helpers =================
static __device__ __forceinline__ void down_lds(const float* Ain, int ldi, int Sin,
                                                float* Aout, int ldo, int Sout,
                                                int tid, int NT){
  int tot = 2*Sout*Sout;
  for (int f=tid; f<tot; f+=NT){
    int img = f/(Sout*Sout), rem = f%(Sout*Sout), y=rem/Sout, x=rem%Sout;
    const float* A = Ain + img*Sin*ldi;
    float s=0.f;
    #pragma unroll
    for (int i=0;i<5;i++){
      int yy=iclamp(2*y+i-2,0,Sin-1);
      float rs=0.f;
      #pragma unroll
      for (int j=0;j<5;j++){
        int xx=iclamp(2*x+j-2,0,Sin-1);
        rs += c_f1d[j]*A[yy*ldi+xx];
      }
      s += c_f1d[i]*rs;
    }
    Aout[img*Sout*ldo + y*ldo + x] = s;
  }
}

static __device__ __forceinline__ void lap_lds(float* Ak, int ldk, int S,
                                               const float* Ag, int ldg,
                                               int tid, int NT){
  int Sg = S>>1;
  int tot = 2*S*S;
  for (int f=tid; f<tot; f+=NT){
    int img=f/(S*S), rem=f%(S*S), y=rem/S, x=rem%S;
    const float* G = Ag + img*Sg*ldg;
    int y2=y>>1, x2=x>>1;
    int ry0,ry1,ry2; float wy0,wy1,wy2;
    if (!(y&1)){ ry0=iclamp(y2-1,0,Sg-1); ry1=y2; ry2=iclamp(y2+1,0,Sg-1); wy0=0.2f; wy1=1.6f; wy2=0.2f; }
    else { ry0=y2; ry1=iclamp(y2+1,0,Sg-1); ry2=y2; wy0=1.f; wy1=1.f; wy2=0.f; }
    int cx0,cx1,cx2; float wx0,wx1,wx2;
    if (!(x&1)){ cx0=iclamp(x2-1,0,Sg-1); cx1=x2; cx2=iclamp(x2+1,0,Sg-1); wx0=0.05f; wx1=0.4f; wx2=0.05f; }
    else { cx0=x2; cx1=iclamp(x2+1,0,Sg-1); cx2=x2; wx0=0.25f; wx1=0.25f; wx2=0.f; }
    float u0 = wx0*G[ry0*ldg+cx0]+wx1*G[ry0*ldg+cx1]+wx2*G[ry0*ldg+cx2];
    float u1 = wx0*G[ry1*ldg+cx0]+wx1*G[ry1*ldg+cx1]+wx2*G[ry1*ldg+cx2];
    float u2 = wx0*G[ry2*ldg+cx0]+wx1*G[ry2*ldg+cx1]+wx2*G[ry2*ldg+cx2];
    Ak[img*S*ldk + y*ldk + x] -= wy0*u0+wy1*u1+wy2*u2;
  }
}

static __device__ __forceinline__ float diff_lds(const float* A, int ld, int S,
                                                 int tid, int NT){
  float v=0.f;
  const float* Ah = A;
  const float* Al = A + S*ld;
  for (int f=tid; f<S*S; f+=NT){
    int y=f/S, x=f%S;
    float dh=SIG0, dl=SIG0;
    #pragma unroll
    for (int i=0;i<5;i++){
      int yy=iclamp(y+i-2,0,S-1);
      #pragma unroll
      for (int j=0;j<5;j++){
        int xx=iclamp(x+j-2,0,S-1);
        float w=c_filt0[i*5+j];
        dh += w*fabsf(Ah[yy*ld+xx]);
        dl += w*fabsf(Al[yy*ld+xx]);
      }
    }
    float d = __fdividef(Ah[y*ld+x],dh) - __fdividef(Al[y*ld+x],dl);
    v += d*d;
  }
  return v;
}

__device__ void tail_body(const float* __restrict__ g3, float* __restrict__ accum,
                          int b, char* smem){
  TS* T = (TS*)smem;
  int tid = threadIdx.x;
  const float* s0  = g3 + (size_t)b*4896 + 148;
  const float* s1p = g3 + (size_t)(b+16)*4896 + 148;
  for (int f=tid; f<2*4096; f+=256){
    int img=f>>12, rem=f&4095, r=rem>>6, c=rem&63;
    T->A3[img][r][c] = (img? s1p : s0)[(size_t)r*72+c];
  }
  __syncthreads();
  down_lds(&T->A3[0][0][0],66,64,&T->A4[0][0][0],34,32,tid,256);
  __syncthreads();
  down_lds(&T->A4[0][0][0],34,32,&T->A5[0][0][0],18,16,tid,256);
  __syncthreads();
  down_lds(&T->A5[0][0][0],18,16,&T->A6[0][0][0],10,8,tid,256);
  __syncthreads();
  lap_lds(&T->A3[0][0][0],66,64,&T->A4[0][0][0],34,tid,256);
  __syncthreads();
  float v3 = diff_lds(&T->A3[0][0][0],66,64,tid,256);
  lap_lds(&T->A4[0][0][0],34,32,&T->A5[0][0][0],18,tid,256);
  __syncthreads();
  float v4 = diff_lds(&T->A4[0][0][0],34,32,tid,256);
  lap_lds(&T->A5[0][0][0],18,16,&T->A6[0][0][0],10,tid,256);
  __syncthreads();
  float v5 = diff_lds(&T->A5[0][0][0],18,16,tid,256);
  float v6 = 0.f;
  for (int f=tid; f<64; f+=256){
    float ch = T->A6[0][f>>3][f&7];
    float cl = T->A6[1][f>>3][f&7];
    float d = __fdividef(ch, fabsf(ch)+SIG1) - __fdividef(cl, fabsf(cl)+SIG1);
    v6 += d*d;
  }
  float vs0=v3, vs1=v4, vs2=v5, vs3=v6;
  #pragma unroll
  for (int k=0;k<4;k++){
    float v = (k==0)?vs0:((k==1)?vs1:((k==2)?vs2:vs3));
    #pragma unroll
    for (int off=32; off>0; off>>=1) v += __shfl_down(v, off);
    if ((tid&63)==0) T->red[tid>>6] = v;
    __syncthreads();
    if (tid==0)
      accum[(3+k)*16 + b] = T->red[0]+T->red[1]+T->red[2]+T->red[3];
    __syncthreads();
  }
}

// ================= dispatch kernels =================
__global__ __launch_bounds__(256)
void k_d2(const float* __restrict__ h, const float* __restrict__ l,
          const float* __restrict__ g1, float* __restrict__ g2,
          float* __restrict__ p0){
  extern __shared__ char smem[];
  if (blockIdx.z < 16){
    int b = blockIdx.z, x0 = blockIdx.x*64, y0 = blockIdx.y*16;
    fused_body<1>((FS*)smem, h+(size_t)b*262144, l+(size_t)b*262144, 0,
                  g1+(size_t)b*68640, g1+(size_t)(b+16)*68640, 264,
                  512, x0, y0, p0 + b*256 + blockIdx.y*8 + blockIdx.x);
  } else {
    int id = (blockIdx.z-16)*256 + blockIdx.y*8 + blockIdx.x;
    int img = id>>5, rem = id&31, xt = rem&1, yt = rem>>1;
    down_body(g1+(size_t)img*68640, g2+(size_t)img*17952, 264, 136, 128, xt*64, yt*8, smem);
  }
}

__global__ __launch_bounds__(256)
void k_d4(const float* __restrict__ g1, float* __restrict__ g2,
          float* __restrict__ g3, float* __restrict__ p1){
  extern __shared__ char smem[];
  if (blockIdx.z < 16){
    int b = blockIdx.z, x0 = blockIdx.x*64, y0 = blockIdx.y*16;
    fused_body<0>((FS*)smem, g1+(size_t)b*68640, g1+(size_t)(b+16)*68640, 264,
                  g2+(size_t)b*17952, g2+(size_t)(b+16)*17952, 136,
                  256, x0, y0, p1 + b*64 + blockIdx.y*4 + blockIdx.x);
  } else {
    int id = (blockIdx.z-16)*64 + blockIdx.y*4 + blockIdx.x;
    int img = id>>3, yt = id&7;
    down_body(g2+(size_t)img*17952, g3+(size_t)img*4896, 136, 72, 64, 0, yt*8, smem);
  }
}

__global__ __launch_bounds__(256)
void k_d5(const float* __restrict__ g2, const float* __restrict__ g3,
          float* __restrict__ p2, float* __restrict__ accum){
  extern __shared__ char smem[];
  if (blockIdx.z < 16){
    int b = blockIdx.z, x0 = blockIdx.x*64, y0 = blockIdx.y*16;
    fused_body<0>((FS*)smem, g2+(size_t)b*17952, g2+(size_t)(b+16)*17952, 136,
                  g3+(size_t)b*4896, g3+(size_t)(b+16)*4896, 72,
                  128, x0, y0, p2 + b*16 + blockIdx.y*2 + blockIdx.x);
  } else {
    int id = blockIdx.y*2 + blockIdx.x;
    tail_body(g3, accum, id, smem);
  }
}

// ================= finalize: reduce partials + formula =================
__global__ __launch_bounds__(256)
void k_d6(const float* __restrict__ p0, const float* __restrict__ p1,
          const float* __restrict__ p2, const float* __restrict__ accum,
          float* __restrict__ out){
  __shared__ float r0[16][16];
  __shared__ float r1[16][4];
  __shared__ float r2[16];
  __shared__ float fin[16];
  int t = threadIdx.x;
  {
    int b = t>>4, c = t&15;
    float s = 0.f;
    #pragma unroll
    for (int j=0;j<16;j++) s += p0[b*256 + c*16 + j];
    r0[b][c] = s;
  }
  if (t < 64){
    int b = t>>2, c = t&3;
    float s = 0.f;
    #pragma unroll
    for (int j=0;j<16;j++) s += p1[b*64 + c*16 + j];
    r1[b][c] = s;
  }
  if (t < 16){
    float s = 0.f;
    #pragma unroll
    for (int j=0;j<16;j++) s += p2[t*16 + j];
    r2[t] = s;
  }
  __syncthreads();
  if (t < 16){
    int b = t;
    float a0 = 0.f;
    #pragma unroll
    for (int c=0;c<16;c++) a0 += r0[b][c];
    float a1 = (r1[b][0]+r1[b][1])+(r1[b][2]+r1[b][3]);
    float a2 = r2[b];
    float m = powf(a0*(1.0f/262144.0f), 0.3f)
            + powf(a1*(1.0f/65536.0f), 0.3f)
            + powf(a2*(1.0f/16384.0f), 0.3f);
    #pragma unroll
    for (int k=3;k<7;k++){
      int hw = (512>>k)*(512>>k);
      m += powf(accum[k*16+b]/(float)hw, 0.3f);
    }
    m *= (1.0f/7.0f);
    fin[b] = powf(m, 1.6666666666666667f);
  }
  __syncthreads();
  if (t == 0){
    float s = 0.f;
    #pragma unroll
    for (int i=0;i<16;i++) s += fin[i];
    out[0] = s * (1.0f/16.0f);
  }
}

extern "C" void kernel_launch(void* const* d_in, const int* in_sizes, int n_in,
                              void* d_out, int out_size, void* d_ws, size_t ws_size,
                              hipStream_t stream){
  const float* h = (const float*)d_in[0];
  const float* l = (const float*)d_in[1];
  float* out = (float*)d_out;
  float* ws = (float*)d_ws;

  float* g1 = ws;                         // 32 * 260*264
  float* g2 = g1 + 2196480;               // 32 * 132*136
  float* g3 = g2 + 574464;                // 32 * 68*72
  float* accum = g3 + 156672;             // 112 ([48..111] written by tail)
  float* p0 = accum + 112;                // 4096 level-0 block partials
  float* p1 = p0 + 4096;                  // 1024 level-1 block partials
  float* p2 = p1 + 1024;                  // 256  level-2 block partials

  size_t fsz = sizeof(FS) > sizeof(DS) ? sizeof(FS) : sizeof(DS);
  size_t tsz = sizeof(TS);

  k_d1<<<dim3(4,32,32), 256, 0, stream>>>(h, l, g1);
  k_d2<<<dim3(8,32,20), 256, fsz, stream>>>(h, l, g1, g2, p0);
  k_d4<<<dim3(4,16,20), 256, fsz, stream>>>(g1, g2, g3, p1);
  k_d5<<<dim3(2,8,17),  256, tsz, stream>>>(g2, g3, p2, accum);
  k_d6<<<1, 256, 0, stream>>>(p0, p1, p2, accum, out);
}